// Round 13
// baseline (320.479 us; speedup 1.0000x reference)
//
#include <hip/hip_runtime.h>
#include <hip/hip_bf16.h>
#include <cstdint>

#define NN 32768          // total nodes
#define NE 524288         // edges (before self-loops)
#define FEAT 256
#define HID 16
#define CSR_CAP (NE + 32 * NN)   // hard bound on padded CSR length (1,572,864)

typedef float f32x16 __attribute__((ext_vector_type(16)));
typedef float f32x8  __attribute__((ext_vector_type(8)));
typedef float f32x4  __attribute__((ext_vector_type(4)));
typedef float f32x2  __attribute__((ext_vector_type(2)));
typedef short s16x8  __attribute__((ext_vector_type(8)));
typedef int   i32x4  __attribute__((ext_vector_type(4)));
typedef int   i32x8  __attribute__((ext_vector_type(8)));

// ---------------- fused init + prepack ----------------
// blocks [0,801): csrp = 0xFF (196608 int4), deg = 0 (8192 int4), dummy row (4 int4)
// block 801: prepack layer-1 w2 -> MFMA B-fragments; block 802: layer-2.
__global__ __launch_bounds__(256) void init_kernel(int4* __restrict__ csrp16,
                                                   int4* __restrict__ deg16,
                                                   int4* __restrict__ dummy16,
                                                   const float* __restrict__ w2a,
                                                   const float* __restrict__ w2b,
                                                   unsigned short* __restrict__ pa,
                                                   unsigned short* __restrict__ pb) {
    int b = blockIdx.x;
    if (b < 801) {
        int g = b * 256 + threadIdx.x;
        if (g < 196608) {
            int4 v = {-1, -1, -1, -1};
            csrp16[g] = v;
        } else if (g < 204800) {
            int4 v = {0, 0, 0, 0};
            deg16[g - 196608] = v;
        } else if (g < 204804) {
            int f = 0xFEFEFEFE;              // ~ -1.69e38
            int4 v = {f, f, f, f};
            dummy16[g - 204800] = v;
        }
    } else {
        const float* w2 = (b == 801) ? w2a : w2b;
        unsigned short* w2p = (b == 801) ? pa : pb;
        #pragma unroll
        for (int rep = 0; rep < 2; ++rep) {
            int wk = threadIdx.x + rep * 256;
            int tt = wk >> 6, l = wk & 63;
            int c = l & 31, kh = l >> 5;
            s16x8 v;
            #pragma unroll
            for (int j = 0; j < 8; ++j) {
                float f = w2[(kh * 8 + j) * FEAT + tt * 32 + c];
                __hip_bfloat16 hb = __float2bfloat16(f);
                v[j] = __builtin_bit_cast(short, hb);
            }
            *(s16x8*)(w2p + (size_t)(tt * 64 + l) * 8) = v;
        }
    }
}

// ---------------- CSR build ----------------
__global__ void hist_kernel(const int* __restrict__ dst, int* __restrict__ deg) {
    int e = blockIdx.x * blockDim.x + threadIdx.x;
    if (e < NE) atomicAdd(&deg[dst[e]], 1);
}

// padded scan: each node's segment length = ceil((deg+1)/32)*32. int4 loads.
__global__ __launch_bounds__(1024) void scan_kernel(const int* __restrict__ deg,
                                                    int* __restrict__ offs,
                                                    int* __restrict__ cur) {
    __shared__ int sums[1024];
    int t = threadIdx.x;
    int base = t * 32;
    const int4* dp = (const int4*)deg + t * 8;
    int4 d4[8];
    #pragma unroll
    for (int i = 0; i < 8; ++i) d4[i] = dp[i];
    int local[32];
    int s = 0;
    #pragma unroll
    for (int i = 0; i < 8; ++i) {
        local[i * 4 + 0] = s; s += (d4[i].x + 32) & ~31;
        local[i * 4 + 1] = s; s += (d4[i].y + 32) & ~31;
        local[i * 4 + 2] = s; s += (d4[i].z + 32) & ~31;
        local[i * 4 + 3] = s; s += (d4[i].w + 32) & ~31;
    }
    sums[t] = s;
    __syncthreads();
    int own = s;
    for (int o = 1; o < 1024; o <<= 1) {
        int v = (t >= o) ? sums[t - o] : 0;
        __syncthreads();
        sums[t] += v;
        __syncthreads();
    }
    int ex = sums[t] - own;   // exclusive prefix
    #pragma unroll
    for (int i = 0; i < 32; ++i) {
        int v = ex + local[i];
        offs[base + i] = v;
        cur[base + i] = v;
    }
    if (t == 1023) offs[NN] = sums[1023];
}

// scatter resolved SRC node ids (ushort); pads remain 0xFFFF from init
__global__ void scatter_kernel(const int* __restrict__ src, const int* __restrict__ dst,
                               int* __restrict__ cur, unsigned short* __restrict__ csrp) {
    int g = blockIdx.x * blockDim.x + threadIdx.x;
    if (g < NE) {
        int pos = atomicAdd(&cur[dst[g]], 1);
        csrp[pos] = (unsigned short)src[g];
    } else if (g < NE + NN) {
        int i = g - NE;
        int pos = atomicAdd(&cur[i], 1);
        csrp[pos] = (unsigned short)i;    // self-loop: src == node
    }
}

// ---------------- p = x @ w1 + 0.5*b1  ([NN,16]) ----------------
__global__ __launch_bounds__(256) void pk_kernel(const float* __restrict__ x,
                                                 const float* __restrict__ w1,
                                                 const float* __restrict__ b1,
                                                 float* __restrict__ p) {
    __shared__ float w1s[16 * 260];   // transposed [j][k], pad to 260
    int t = threadIdx.x;
    for (int u = t; u < 4096; u += 256) {
        int k = u >> 4, j = u & 15;
        w1s[j * 260 + k] = w1[u];
    }
    __syncthreads();
    int gid = blockIdx.x * 256 + t;
    int i = gid >> 4, j = gid & 15;
    float acc = 0.5f * b1[j];
    const float* xr = x + (size_t)i * FEAT;
    const float* wr = w1s + j * 260;
    #pragma unroll 8
    for (int k = 0; k < 256; k += 4) {
        float4 xv = *(const float4*)(xr + k);
        float4 wv = *(const float4*)(wr + k);
        acc = fmaf(xv.x, wv.x, acc);
        acc = fmaf(xv.y, wv.y, acc);
        acc = fmaf(xv.z, wv.z, acc);
        acc = fmaf(xv.w, wv.w, acc);
    }
    p[gid] = acc;
}

// ---------------- edge MLP + aggregation via MFMA ----------------
// Grid-strided: each wave owns (half -> 4 col-tiles) x 8 consecutive nodes.
// Conversion and relu-rowsum epilogue use ext_vector ops -> packed v_pk_*_f32.
// Per 32-edge tile: A = h[32 edges][16] split hi = trunc16(h) (exact mask),
// lo = h - hi (exact, h >= 0), packed via v_perm_b32. |err| <= 2^-16 |h|.
// Pads resolve to dummy row p[NN] = -1.7e38 -> h = 0 (sp = min(s, NN)).
// C preloaded with bias; pad rows contribute relu(b2), cancelled via npad.
// sched_barrier(0) per tt bounds C-tile liveness (r12: VGPR 76->48, occ +12pt).
// NO min-waves launch_bounds cap (r6: cap below demand => 2.3 GB scratch spill).
__global__ __launch_bounds__(256) void edge_mfma_kernel(
    const float* __restrict__ p, const unsigned short* __restrict__ w2p,
    const float* __restrict__ b2, const unsigned short* __restrict__ csrp,
    const int* __restrict__ offs, const int* __restrict__ cur,
    float* __restrict__ out)
{
    int wid = threadIdx.x >> 6, lane = threadIdx.x & 63;
    int gw = __builtin_amdgcn_readfirstlane(blockIdx.x * 4 + wid);  // SGPR wave id
    int t0 = (gw & 1) * 4;                // this wave's col-tile base
    int nodeBase = (gw >> 1) * 8;         // 8 consecutive nodes per wave
    int r31 = lane & 31;          // A-row (edge slot) AND C-col
    int kh  = lane >> 5;          // k-half: k = kh*8 + j

    s16x8 B[4];
    #pragma unroll
    for (int tt = 0; tt < 4; ++tt)
        B[tt] = *(const s16x8*)(w2p + (size_t)((t0 + tt) * 64 + lane) * 8);

    float b2r[4], rb2[4];
    #pragma unroll
    for (int tt = 0; tt < 4; ++tt) {
        b2r[tt] = b2[(t0 + tt) * 32 + r31];
        rb2[tt] = fmaxf(b2r[tt], 0.f);
    }

    const int M16 = (int)0xFFFF0000;
    const i32x8 K8 = {M16, M16, M16, M16, M16, M16, M16, M16};

    #pragma unroll 1
    for (int u = 0; u < 8; ++u) {
        int node = nodeBase + u;          // SGPR

        f32x8 pd8;
        {
            float4 q0 = *(const float4*)(p + node * HID + kh * 8);
            float4 q1 = *(const float4*)(p + node * HID + kh * 8 + 4);
            pd8[0] = q0.x; pd8[1] = q0.y; pd8[2] = q0.z; pd8[3] = q0.w;
            pd8[4] = q1.x; pd8[5] = q1.y; pd8[6] = q1.z; pd8[7] = q1.w;
        }

        int rs = offs[node], re = offs[node + 1];
        int npad = re - cur[node];        // cur[node] = rs + (deg+1) after scatter

        float racc[4] = {0.f, 0.f, 0.f, 0.f};

        for (int pos = rs; pos < re; pos += 32) {
            int s = csrp[pos + r31];             // zero-extended ushort; pad = 65535
            int sp = min(s, NN);                 // pad -> dummy row (p[NN] = -1.7e38)
            const float* ps = p + sp * HID + kh * 8;
            float4 a0 = *(const float4*)ps;
            float4 a1 = *(const float4*)(ps + 4);
            f32x8 av = {a0.x, a0.y, a0.z, a0.w, a1.x, a1.y, a1.z, a1.w};

            f32x8 h8 = __builtin_elementwise_max(av + pd8, (f32x8){});
            i32x8 c8 = __builtin_bit_cast(i32x8, h8);
            i32x8 m8 = c8 & K8;
            f32x8 r8 = h8 - __builtin_bit_cast(f32x8, m8);
            i32x8 rc = __builtin_bit_cast(i32x8, r8);

            i32x4 hi4, lo4;
            hi4[0] = __builtin_amdgcn_perm(c8[1], c8[0], 0x07060302);
            hi4[1] = __builtin_amdgcn_perm(c8[3], c8[2], 0x07060302);
            hi4[2] = __builtin_amdgcn_perm(c8[5], c8[4], 0x07060302);
            hi4[3] = __builtin_amdgcn_perm(c8[7], c8[6], 0x07060302);
            lo4[0] = __builtin_amdgcn_perm(rc[1], rc[0], 0x07060302);
            lo4[1] = __builtin_amdgcn_perm(rc[3], rc[2], 0x07060302);
            lo4[2] = __builtin_amdgcn_perm(rc[5], rc[4], 0x07060302);
            lo4[3] = __builtin_amdgcn_perm(rc[7], rc[6], 0x07060302);

            s16x8 Ahi = __builtin_bit_cast(s16x8, hi4);
            s16x8 Alo = __builtin_bit_cast(s16x8, lo4);

            #pragma unroll
            for (int tt = 0; tt < 4; ++tt) {
                float bb = b2r[tt];
                f32x16 C = {bb,bb,bb,bb,bb,bb,bb,bb,bb,bb,bb,bb,bb,bb,bb,bb};
                C = __builtin_amdgcn_mfma_f32_32x32x16_bf16(Ahi, B[tt], C, 0, 0, 0);
                C = __builtin_amdgcn_mfma_f32_32x32x16_bf16(Alo, B[tt], C, 0, 0, 0);
                C = __builtin_elementwise_max(C, (f32x16){});
                f32x8 s8 = __builtin_shufflevector(C, C, 0, 1, 2, 3, 4, 5, 6, 7)
                         + __builtin_shufflevector(C, C, 8, 9, 10, 11, 12, 13, 14, 15);
                f32x4 s4 = __builtin_shufflevector(s8, s8, 0, 1, 2, 3)
                         + __builtin_shufflevector(s8, s8, 4, 5, 6, 7);
                f32x2 s2 = __builtin_shufflevector(s4, s4, 0, 1)
                         + __builtin_shufflevector(s4, s4, 2, 3);
                racc[tt] += s2[0] + s2[1];
                __builtin_amdgcn_sched_barrier(0);   // bound C-tile liveness to 1
            }
        }

        #pragma unroll
        for (int tt = 0; tt < 4; ++tt) {
            racc[tt] += __shfl_xor(racc[tt], 32, 64);    // combine row-halves
            racc[tt] -= (float)npad * rb2[tt];           // cancel pad rows
        }

        // each half-wave writes 2 of the 4 col-tiles (values identical post-shfl)
        float* ob = out + (size_t)node * FEAT + r31;
        if (kh == 0) {
            ob[(t0 + 0) * 32] = racc[0];
            ob[(t0 + 1) * 32] = racc[1];
        } else {
            ob[(t0 + 2) * 32] = racc[2];
            ob[(t0 + 3) * 32] = racc[3];
        }
    }
}

// ---------------- readout GEMM1 partials: y1part[kb][256][64] ----------------
// 8 waves x 128-k slice. w staged in 64 VGPRs (coalesced); y read as
// wave-uniform broadcast float4 loads feeding fma directly (no readlane).
__global__ __launch_bounds__(512) void ro1_kernel(const float* __restrict__ y,
                                                  const float* __restrict__ w1,
                                                  float* __restrict__ y1part) {
    int mb = blockIdx.x >> 5;            // 0..15
    int kb = blockIdx.x & 31;            // 0..31
    int t = threadIdx.x;
    int ks = t >> 6;                     // wave 0..7
    int lane = t & 63;                   // n column

    float acc[16];
    #pragma unroll
    for (int m = 0; m < 16; ++m) acc[m] = 0.f;

    int kslice = kb * 1024 + ks * 128;
    #pragma unroll 1
    for (int c4 = 0; c4 < 2; ++c4) {
        int k0 = kslice + c4 * 64;
        float wreg[64];
        const float* wp = w1 + (size_t)k0 * 64 + lane;
        #pragma unroll
        for (int kk = 0; kk < 64; ++kk) wreg[kk] = wp[(size_t)kk * 64];  // coalesced
        const float* yb = y + (size_t)(mb * 16) * 32768 + k0;
        #pragma unroll
        for (int m = 0; m < 16; ++m) {
            const float4* yp = (const float4*)(yb + (size_t)m * 32768);  // uniform
            #pragma unroll
            for (int q = 0; q < 16; ++q) {
                float4 yv = yp[q];                                       // broadcast
                acc[m] = fmaf(yv.x, wreg[q * 4 + 0], acc[m]);
                acc[m] = fmaf(yv.y, wreg[q * 4 + 1], acc[m]);
                acc[m] = fmaf(yv.z, wreg[q * 4 + 2], acc[m]);
                acc[m] = fmaf(yv.w, wreg[q * 4 + 3], acc[m]);
            }
        }
    }

    __shared__ float red[512 * 17];      // 34.8 KB
    #pragma unroll
    for (int m = 0; m < 16; ++m) red[t * 17 + m] = acc[m];
    __syncthreads();
    #pragma unroll
    for (int i = 0; i < 2; ++i) {
        int u = t + i * 512;
        int m = u >> 6, nn = u & 63;
        float v = 0.f;
        #pragma unroll
        for (int k8 = 0; k8 < 8; ++k8) v += red[(k8 * 64 + nn) * 17 + m];
        y1part[(size_t)kb * 16384 + (mb * 16 + m) * 64 + nn] = v;   // race-free
    }
}

// ---------------- readout GEMM2 (fused y1 reduce+bias+relu): out = relu(y1 @ w2 + b2) ----------------
__global__ __launch_bounds__(256) void ro2_kernel(const float* __restrict__ y1part,
                                                  const float* __restrict__ b1,
                                                  const float* __restrict__ w2,
                                                  const float* __restrict__ b2,
                                                  float* __restrict__ out) {
    __shared__ float yls[64 * 68];
    int mt = blockIdx.x >> 6;            // 4 m-tiles of 64
    int nt = blockIdx.x & 63;            // 64 n-tiles of 256
    int t = threadIdx.x;
    for (int u = t; u < 4096; u += 256) {
        int row = u >> 6, col = u & 63;
        int m = mt * 64 + row;
        float s = b1[col];
        #pragma unroll 8
        for (int kb = 0; kb < 32; ++kb) s += y1part[(size_t)kb * 16384 + m * 64 + col];
        yls[row * 68 + col] = fmaxf(s, 0.f);
    }
    __syncthreads();

    int n = nt * 256 + t;
    float w2r[64];
    #pragma unroll
    for (int jj = 0; jj < 64; ++jj) w2r[jj] = w2[(size_t)jj * 16384 + n];
    float bb = b2[n];
    for (int m = 0; m < 64; ++m) {
        float acc = bb;
        const float* yr = &yls[m * 68];
        #pragma unroll
        for (int jj = 0; jj < 64; jj += 4) {
            float4 yv = *(const float4*)(yr + jj);
            acc = fmaf(yv.x, w2r[jj],     acc);
            acc = fmaf(yv.y, w2r[jj + 1], acc);
            acc = fmaf(yv.z, w2r[jj + 2], acc);
            acc = fmaf(yv.w, w2r[jj + 3], acc);
        }
        out[(size_t)(mt * 64 + m) * 16384 + n] = fmaxf(acc, 0.f);
    }
}

extern "C" void kernel_launch(void* const* d_in, const int* in_sizes, int n_in,
                              void* d_out, int out_size, void* d_ws, size_t ws_size,
                              hipStream_t stream) {
    (void)in_sizes; (void)n_in; (void)out_size; (void)ws_size;
    const float* x      = (const float*)d_in[0];
    const int*   ei     = (const int*)d_in[1];     // [2, NE] : row0 src, row1 dst
    const float* mp1_w1 = (const float*)d_in[2];
    const float* mp1_b1 = (const float*)d_in[3];
    const float* mp1_w2 = (const float*)d_in[4];
    const float* mp1_b2 = (const float*)d_in[5];
    const float* mp2_w1 = (const float*)d_in[6];
    const float* mp2_b1 = (const float*)d_in[7];
    const float* mp2_w2 = (const float*)d_in[8];
    const float* mp2_b2 = (const float*)d_in[9];
    const float* ro_w1  = (const float*)d_in[10];
    const float* ro_b1  = (const float*)d_in[11];
    const float* ro_w2  = (const float*)d_in[12];
    const float* ro_b2  = (const float*)d_in[13];
    float* out = (float*)d_out;

    // workspace carve-up (~39.3 MB). p has NN+1 rows: row NN is the pad dummy
    // (-1.7e38). y1part aliases p's first 524288 floats (p dead by readout).
    float* p      = (float*)d_ws;                    // (NN+1)*16 = 524304 floats
    float* y1part = p;                               // alias (524288 floats)
    float* x1     = p + 524304;                      // NN*256
    int*   deg    = (int*)(x1 + (size_t)NN * FEAT);  // NN
    int*   offs   = deg + NN;                        // NN+1
    int*   cur    = offs + NN + 1;                   // NN (+3 pad for 16B align)
    unsigned short* csrp = (unsigned short*)(cur + NN + 3);  // CSR_CAP (16B aligned)
    unsigned short* w2p1 = csrp + CSR_CAP;           // 4096 (16B aligned)
    unsigned short* w2p2 = w2p1 + 4096;              // 4096

    const int* src = ei;
    const int* dst = ei + NE;

    // fused init + prepack (blocks 801/802 pack both layers' w2)
    init_kernel<<<803, 256, 0, stream>>>((int4*)csrp, (int4*)deg,
                                         (int4*)(p + (size_t)NN * HID),
                                         mp1_w2, mp2_w2, w2p1, w2p2);

    hist_kernel<<<NE / 256, 256, 0, stream>>>(dst, deg);
    scan_kernel<<<1, 1024, 0, stream>>>(deg, offs, cur);
    scatter_kernel<<<(NE + NN) / 256, 256, 0, stream>>>(src, dst, cur, csrp);

    // layer 1 (2 waves x 8 nodes each -> NN*2/8 waves -> NN/16 blocks)
    pk_kernel<<<(NN * HID) / 256, 256, 0, stream>>>(x, mp1_w1, mp1_b1, p);
    edge_mfma_kernel<<<NN / 16, 256, 0, stream>>>(p, w2p1, mp1_b2, csrp, offs, cur, x1);
    // layer 2
    pk_kernel<<<(NN * HID) / 256, 256, 0, stream>>>(x1, mp2_w1, mp2_b1, p);
    edge_mfma_kernel<<<NN / 16, 256, 0, stream>>>(p, w2p2, mp2_b2, csrp, offs, cur, x1);

    // readout (p dead; y1part reuses its storage)
    ro1_kernel<<<512, 512, 0, stream>>>(x1, ro_w1, y1part);
    ro2_kernel<<<256, 256, 0, stream>>>(y1part, ro_b1, ro_w2, ro_b2, out);
}

// Round 14
// 289.933 us; speedup vs baseline: 1.1054x; 1.1054x over previous
//
#include <hip/hip_runtime.h>
#include <hip/hip_bf16.h>
#include <cstdint>

#define NN 32768          // total nodes
#define NE 524288         // edges (before self-loops)
#define FEAT 256
#define HID 16
#define CSR_CAP (NE + 32 * NN)   // hard bound on padded CSR length (1,572,864)

typedef float f32x16 __attribute__((ext_vector_type(16)));
typedef float f32x8  __attribute__((ext_vector_type(8)));
typedef float f32x4  __attribute__((ext_vector_type(4)));
typedef float f32x2  __attribute__((ext_vector_type(2)));
typedef short s16x8  __attribute__((ext_vector_type(8)));
typedef int   i32x4  __attribute__((ext_vector_type(4)));
typedef int   i32x8  __attribute__((ext_vector_type(8)));

// ---------------- fused init + prepack ----------------
// blocks [0,801): csrp = 0xFF, deg = 0, dummy p-row = -1.7e38
// block 801: prepack layer-1 w2; block 802: layer-2 w2
// blocks [803, 803+1024): prepack ro_w1 -> single-bf16 B-fragments (4 MB)
__global__ __launch_bounds__(256) void init_kernel(int4* __restrict__ csrp16,
                                                   int4* __restrict__ deg16,
                                                   int4* __restrict__ dummy16,
                                                   const float* __restrict__ w2a,
                                                   const float* __restrict__ w2b,
                                                   unsigned short* __restrict__ pa,
                                                   unsigned short* __restrict__ pb,
                                                   const float* __restrict__ row1,
                                                   unsigned short* __restrict__ w1bf) {
    int b = blockIdx.x;
    if (b < 801) {
        int g = b * 256 + threadIdx.x;
        if (g < 196608) {
            int4 v = {-1, -1, -1, -1};
            csrp16[g] = v;
        } else if (g < 204800) {
            int4 v = {0, 0, 0, 0};
            deg16[g - 196608] = v;
        } else if (g < 204804) {
            int f = 0xFEFEFEFE;              // ~ -1.69e38
            int4 v = {f, f, f, f};
            dummy16[g - 204800] = v;
        }
    } else if (b < 803) {
        const float* w2 = (b == 801) ? w2a : w2b;
        unsigned short* w2p = (b == 801) ? pa : pb;
        #pragma unroll
        for (int rep = 0; rep < 2; ++rep) {
            int wk = threadIdx.x + rep * 256;
            int tt = wk >> 6, l = wk & 63;
            int c = l & 31, kh = l >> 5;
            s16x8 v;
            #pragma unroll
            for (int j = 0; j < 8; ++j) {
                float f = w2[(kh * 8 + j) * FEAT + tt * 32 + c];
                __hip_bfloat16 hb = __float2bfloat16(f);
                v[j] = __builtin_bit_cast(short, hb);
            }
            *(s16x8*)(w2p + (size_t)(tt * 64 + l) * 8) = v;
        }
    } else {
        // ro_w1 [32768][64] -> B-frag layout [ktile 0..2047][ntile 0..1][lane][8]
        int f = (b - 803) * 256 + threadIdx.x;   // 0..262143
        int ktile = f >> 7;
        int rem = f & 127;
        int nt = rem >> 6, l = rem & 63;
        int col = nt * 32 + (l & 31);
        int kb = ktile * 16 + (l >> 5) * 8;
        s16x8 v;
        #pragma unroll
        for (int j = 0; j < 8; ++j) {
            float w = row1[(size_t)(kb + j) * 64 + col];
            __hip_bfloat16 hb = __float2bfloat16(w);   // RNE single bf16
            v[j] = __builtin_bit_cast(short, hb);
        }
        *(s16x8*)(w1bf + (size_t)f * 8) = v;
    }
}

// ---------------- CSR build ----------------
__global__ void hist_kernel(const int* __restrict__ dst, int* __restrict__ deg) {
    int e = blockIdx.x * blockDim.x + threadIdx.x;
    if (e < NE) atomicAdd(&deg[dst[e]], 1);
}

// padded scan: each node's segment length = ceil((deg+1)/32)*32. int4 loads.
__global__ __launch_bounds__(1024) void scan_kernel(const int* __restrict__ deg,
                                                    int* __restrict__ offs,
                                                    int* __restrict__ cur) {
    __shared__ int sums[1024];
    int t = threadIdx.x;
    int base = t * 32;
    const int4* dp = (const int4*)deg + t * 8;
    int4 d4[8];
    #pragma unroll
    for (int i = 0; i < 8; ++i) d4[i] = dp[i];
    int local[32];
    int s = 0;
    #pragma unroll
    for (int i = 0; i < 8; ++i) {
        local[i * 4 + 0] = s; s += (d4[i].x + 32) & ~31;
        local[i * 4 + 1] = s; s += (d4[i].y + 32) & ~31;
        local[i * 4 + 2] = s; s += (d4[i].z + 32) & ~31;
        local[i * 4 + 3] = s; s += (d4[i].w + 32) & ~31;
    }
    sums[t] = s;
    __syncthreads();
    int own = s;
    for (int o = 1; o < 1024; o <<= 1) {
        int v = (t >= o) ? sums[t - o] : 0;
        __syncthreads();
        sums[t] += v;
        __syncthreads();
    }
    int ex = sums[t] - own;   // exclusive prefix
    #pragma unroll
    for (int i = 0; i < 32; ++i) {
        int v = ex + local[i];
        offs[base + i] = v;
        cur[base + i] = v;
    }
    if (t == 1023) offs[NN] = sums[1023];
}

// scatter resolved SRC node ids (ushort); pads remain 0xFFFF from init
__global__ void scatter_kernel(const int* __restrict__ src, const int* __restrict__ dst,
                               int* __restrict__ cur, unsigned short* __restrict__ csrp) {
    int g = blockIdx.x * blockDim.x + threadIdx.x;
    if (g < NE) {
        int pos = atomicAdd(&cur[dst[g]], 1);
        csrp[pos] = (unsigned short)src[g];
    } else if (g < NE + NN) {
        int i = g - NE;
        int pos = atomicAdd(&cur[i], 1);
        csrp[pos] = (unsigned short)i;    // self-loop: src == node
    }
}

// ---------------- p = x @ w1 + 0.5*b1  ([NN,16]) ----------------
__global__ __launch_bounds__(256) void pk_kernel(const float* __restrict__ x,
                                                 const float* __restrict__ w1,
                                                 const float* __restrict__ b1,
                                                 float* __restrict__ p) {
    __shared__ float w1s[16 * 260];   // transposed [j][k], pad to 260
    int t = threadIdx.x;
    for (int u = t; u < 4096; u += 256) {
        int k = u >> 4, j = u & 15;
        w1s[j * 260 + k] = w1[u];
    }
    __syncthreads();
    int gid = blockIdx.x * 256 + t;
    int i = gid >> 4, j = gid & 15;
    float acc = 0.5f * b1[j];
    const float* xr = x + (size_t)i * FEAT;
    const float* wr = w1s + j * 260;
    #pragma unroll 8
    for (int k = 0; k < 256; k += 4) {
        float4 xv = *(const float4*)(xr + k);
        float4 wv = *(const float4*)(wr + k);
        acc = fmaf(xv.x, wv.x, acc);
        acc = fmaf(xv.y, wv.y, acc);
        acc = fmaf(xv.z, wv.z, acc);
        acc = fmaf(xv.w, wv.w, acc);
    }
    p[gid] = acc;
}

// ---------------- edge MLP + aggregation via MFMA (r12/r13 validated) ----------------
__global__ __launch_bounds__(256) void edge_mfma_kernel(
    const float* __restrict__ p, const unsigned short* __restrict__ w2p,
    const float* __restrict__ b2, const unsigned short* __restrict__ csrp,
    const int* __restrict__ offs, const int* __restrict__ cur,
    float* __restrict__ out)
{
    int wid = threadIdx.x >> 6, lane = threadIdx.x & 63;
    int gw = __builtin_amdgcn_readfirstlane(blockIdx.x * 4 + wid);  // SGPR wave id
    int t0 = (gw & 1) * 4;                // this wave's col-tile base
    int nodeBase = (gw >> 1) * 8;         // 8 consecutive nodes per wave
    int r31 = lane & 31;          // A-row (edge slot) AND C-col
    int kh  = lane >> 5;          // k-half: k = kh*8 + j

    s16x8 B[4];
    #pragma unroll
    for (int tt = 0; tt < 4; ++tt)
        B[tt] = *(const s16x8*)(w2p + (size_t)((t0 + tt) * 64 + lane) * 8);

    float b2r[4], rb2[4];
    #pragma unroll
    for (int tt = 0; tt < 4; ++tt) {
        b2r[tt] = b2[(t0 + tt) * 32 + r31];
        rb2[tt] = fmaxf(b2r[tt], 0.f);
    }

    const int M16 = (int)0xFFFF0000;
    const i32x8 K8 = {M16, M16, M16, M16, M16, M16, M16, M16};

    #pragma unroll 1
    for (int u = 0; u < 8; ++u) {
        int node = nodeBase + u;          // SGPR

        f32x8 pd8;
        {
            float4 q0 = *(const float4*)(p + node * HID + kh * 8);
            float4 q1 = *(const float4*)(p + node * HID + kh * 8 + 4);
            pd8[0] = q0.x; pd8[1] = q0.y; pd8[2] = q0.z; pd8[3] = q0.w;
            pd8[4] = q1.x; pd8[5] = q1.y; pd8[6] = q1.z; pd8[7] = q1.w;
        }

        int rs = offs[node], re = offs[node + 1];
        int npad = re - cur[node];        // cur[node] = rs + (deg+1) after scatter

        float racc[4] = {0.f, 0.f, 0.f, 0.f};

        for (int pos = rs; pos < re; pos += 32) {
            int s = csrp[pos + r31];             // zero-extended ushort; pad = 65535
            int sp = min(s, NN);                 // pad -> dummy row (p[NN] = -1.7e38)
            const float* ps = p + sp * HID + kh * 8;
            float4 a0 = *(const float4*)ps;
            float4 a1 = *(const float4*)(ps + 4);
            f32x8 av = {a0.x, a0.y, a0.z, a0.w, a1.x, a1.y, a1.z, a1.w};

            f32x8 h8 = __builtin_elementwise_max(av + pd8, (f32x8){});
            i32x8 c8 = __builtin_bit_cast(i32x8, h8);
            i32x8 m8 = c8 & K8;
            f32x8 r8 = h8 - __builtin_bit_cast(f32x8, m8);
            i32x8 rc = __builtin_bit_cast(i32x8, r8);

            i32x4 hi4, lo4;
            hi4[0] = __builtin_amdgcn_perm(c8[1], c8[0], 0x07060302);
            hi4[1] = __builtin_amdgcn_perm(c8[3], c8[2], 0x07060302);
            hi4[2] = __builtin_amdgcn_perm(c8[5], c8[4], 0x07060302);
            hi4[3] = __builtin_amdgcn_perm(c8[7], c8[6], 0x07060302);
            lo4[0] = __builtin_amdgcn_perm(rc[1], rc[0], 0x07060302);
            lo4[1] = __builtin_amdgcn_perm(rc[3], rc[2], 0x07060302);
            lo4[2] = __builtin_amdgcn_perm(rc[5], rc[4], 0x07060302);
            lo4[3] = __builtin_amdgcn_perm(rc[7], rc[6], 0x07060302);

            s16x8 Ahi = __builtin_bit_cast(s16x8, hi4);
            s16x8 Alo = __builtin_bit_cast(s16x8, lo4);

            #pragma unroll
            for (int tt = 0; tt < 4; ++tt) {
                float bb = b2r[tt];
                f32x16 C = {bb,bb,bb,bb,bb,bb,bb,bb,bb,bb,bb,bb,bb,bb,bb,bb};
                C = __builtin_amdgcn_mfma_f32_32x32x16_bf16(Ahi, B[tt], C, 0, 0, 0);
                C = __builtin_amdgcn_mfma_f32_32x32x16_bf16(Alo, B[tt], C, 0, 0, 0);
                C = __builtin_elementwise_max(C, (f32x16){});
                f32x8 s8 = __builtin_shufflevector(C, C, 0, 1, 2, 3, 4, 5, 6, 7)
                         + __builtin_shufflevector(C, C, 8, 9, 10, 11, 12, 13, 14, 15);
                f32x4 s4 = __builtin_shufflevector(s8, s8, 0, 1, 2, 3)
                         + __builtin_shufflevector(s8, s8, 4, 5, 6, 7);
                f32x2 s2 = __builtin_shufflevector(s4, s4, 0, 1)
                         + __builtin_shufflevector(s4, s4, 2, 3);
                racc[tt] += s2[0] + s2[1];
                __builtin_amdgcn_sched_barrier(0);   // bound C-tile liveness to 1
            }
        }

        #pragma unroll
        for (int tt = 0; tt < 4; ++tt) {
            racc[tt] += __shfl_xor(racc[tt], 32, 64);    // combine row-halves
            racc[tt] -= (float)npad * rb2[tt];           // cancel pad rows
        }

        float* ob = out + (size_t)node * FEAT + r31;
        if (kh == 0) {
            ob[(t0 + 0) * 32] = racc[0];
            ob[(t0 + 1) * 32] = racc[1];
        } else {
            ob[(t0 + 2) * 32] = racc[2];
            ob[(t0 + 3) * 32] = racc[3];
        }
    }
}

// ---------------- readout GEMM1 via MFMA: y1part[ks][256][64] ----------------
// 512 waves: m-tile (8, 32 rows) x k-split (64, 512 k each). Per 16-k tile:
// A = y-tile split hi/lo (y >= 0, trunc exact, perm-packed); B = prepacked
// single-bf16 w1 fragments. C: 2 n-tiles x 16 AGPR. Race-free partial stores.
__global__ __launch_bounds__(256) void ro1_kernel(const float* __restrict__ y,
                                                  const unsigned short* __restrict__ w1bf,
                                                  float* __restrict__ y1part) {
    int wid = threadIdx.x >> 6, lane = threadIdx.x & 63;
    int gw = blockIdx.x * 4 + wid;       // 0..511
    int mt = gw >> 6;                    // 0..7
    int ks = gw & 63;                    // 0..63
    int r31 = lane & 31;
    int kh  = lane >> 5;

    const float* yr = y + (size_t)(mt * 32 + r31) * 32768 + kh * 8;

    const int M16 = (int)0xFFFF0000;
    const i32x8 K8 = {M16, M16, M16, M16, M16, M16, M16, M16};

    f32x16 C0 = {}, C1 = {};

    #pragma unroll 4
    for (int kt = 0; kt < 32; ++kt) {
        int ktile = ks * 32 + kt;
        int kb = ktile * 16;

        float4 a0 = *(const float4*)(yr + kb);
        float4 a1 = *(const float4*)(yr + kb + 4);
        f32x8 av = {a0.x, a0.y, a0.z, a0.w, a1.x, a1.y, a1.z, a1.w};

        i32x8 c8 = __builtin_bit_cast(i32x8, av);
        i32x8 m8 = c8 & K8;
        f32x8 r8 = av - __builtin_bit_cast(f32x8, m8);
        i32x8 rc = __builtin_bit_cast(i32x8, r8);

        i32x4 hi4, lo4;
        hi4[0] = __builtin_amdgcn_perm(c8[1], c8[0], 0x07060302);
        hi4[1] = __builtin_amdgcn_perm(c8[3], c8[2], 0x07060302);
        hi4[2] = __builtin_amdgcn_perm(c8[5], c8[4], 0x07060302);
        hi4[3] = __builtin_amdgcn_perm(c8[7], c8[6], 0x07060302);
        lo4[0] = __builtin_amdgcn_perm(rc[1], rc[0], 0x07060302);
        lo4[1] = __builtin_amdgcn_perm(rc[3], rc[2], 0x07060302);
        lo4[2] = __builtin_amdgcn_perm(rc[5], rc[4], 0x07060302);
        lo4[3] = __builtin_amdgcn_perm(rc[7], rc[6], 0x07060302);

        s16x8 Ahi = __builtin_bit_cast(s16x8, hi4);
        s16x8 Alo = __builtin_bit_cast(s16x8, lo4);

        s16x8 B0 = *(const s16x8*)(w1bf + ((size_t)(ktile * 2 + 0) * 64 + lane) * 8);
        s16x8 B1 = *(const s16x8*)(w1bf + ((size_t)(ktile * 2 + 1) * 64 + lane) * 8);

        C0 = __builtin_amdgcn_mfma_f32_32x32x16_bf16(Ahi, B0, C0, 0, 0, 0);
        C0 = __builtin_amdgcn_mfma_f32_32x32x16_bf16(Alo, B0, C0, 0, 0, 0);
        C1 = __builtin_amdgcn_mfma_f32_32x32x16_bf16(Ahi, B1, C1, 0, 0, 0);
        C1 = __builtin_amdgcn_mfma_f32_32x32x16_bf16(Alo, B1, C1, 0, 0, 0);
    }

    // C layout: col = lane&31, row = (reg&3) + 8*(reg>>2) + 4*(lane>>5)
    float* yp = y1part + (size_t)ks * 16384 + (size_t)(mt * 32) * 64;
    #pragma unroll
    for (int reg = 0; reg < 16; ++reg) {
        int row = (reg & 3) + 8 * (reg >> 2) + 4 * kh;
        yp[row * 64 + r31]      = C0[reg];
        yp[row * 64 + 32 + r31] = C1[reg];
    }
}

// ---------------- readout GEMM2 (fused y1 reduce+bias+relu): out = relu(y1 @ w2 + b2) ----------------
__global__ __launch_bounds__(256) void ro2_kernel(const float* __restrict__ y1part,
                                                  const float* __restrict__ b1,
                                                  const float* __restrict__ w2,
                                                  const float* __restrict__ b2,
                                                  float* __restrict__ out) {
    __shared__ float yls[64 * 68];
    int mt = blockIdx.x >> 6;            // 4 m-tiles of 64
    int nt = blockIdx.x & 63;            // 64 n-tiles of 256
    int t = threadIdx.x;
    for (int u = t; u < 4096; u += 256) {
        int row = u >> 6, col = u & 63;
        int m = mt * 64 + row;
        float s = b1[col];
        #pragma unroll 8
        for (int kb = 0; kb < 64; ++kb) s += y1part[(size_t)kb * 16384 + m * 64 + col];
        yls[row * 68 + col] = fmaxf(s, 0.f);
    }
    __syncthreads();

    int n = nt * 256 + t;
    float w2r[64];
    #pragma unroll
    for (int jj = 0; jj < 64; ++jj) w2r[jj] = w2[(size_t)jj * 16384 + n];
    float bb = b2[n];
    for (int m = 0; m < 64; ++m) {
        float acc = bb;
        const float* yr = &yls[m * 68];
        #pragma unroll
        for (int jj = 0; jj < 64; jj += 4) {
            float4 yv = *(const float4*)(yr + jj);
            acc = fmaf(yv.x, w2r[jj],     acc);
            acc = fmaf(yv.y, w2r[jj + 1], acc);
            acc = fmaf(yv.z, w2r[jj + 2], acc);
            acc = fmaf(yv.w, w2r[jj + 3], acc);
        }
        out[(size_t)(mt * 64 + m) * 16384 + n] = fmaxf(acc, 0.f);
    }
}

extern "C" void kernel_launch(void* const* d_in, const int* in_sizes, int n_in,
                              void* d_out, int out_size, void* d_ws, size_t ws_size,
                              hipStream_t stream) {
    (void)in_sizes; (void)n_in; (void)out_size; (void)ws_size;
    const float* x      = (const float*)d_in[0];
    const int*   ei     = (const int*)d_in[1];     // [2, NE] : row0 src, row1 dst
    const float* mp1_w1 = (const float*)d_in[2];
    const float* mp1_b1 = (const float*)d_in[3];
    const float* mp1_w2 = (const float*)d_in[4];
    const float* mp1_b2 = (const float*)d_in[5];
    const float* mp2_w1 = (const float*)d_in[6];
    const float* mp2_b1 = (const float*)d_in[7];
    const float* mp2_w2 = (const float*)d_in[8];
    const float* mp2_b2 = (const float*)d_in[9];
    const float* ro_w1  = (const float*)d_in[10];
    const float* ro_b1  = (const float*)d_in[11];
    const float* ro_w2  = (const float*)d_in[12];
    const float* ro_b2  = (const float*)d_in[13];
    float* out = (float*)d_out;

    // workspace carve-up (~43.3 MB), reordered so [p..csrp] is a contiguous
    // 5.6 MB region that y1part (64*16384 floats = 4.2 MB) aliases after the
    // edge layers (p/deg/offs/cur/csrp all dead by readout).
    float* x1     = (float*)d_ws;                    // NN*256
    float* p      = x1 + (size_t)NN * FEAT;          // (NN+1)*16 = 524304 floats
    int*   deg    = (int*)(p + 524304);              // NN
    int*   offs   = deg + NN;                        // NN+1
    int*   cur    = offs + NN + 1;                   // NN (+3 pad for 16B align)
    unsigned short* csrp = (unsigned short*)(cur + NN + 3);  // CSR_CAP (16B aligned)
    unsigned short* w2p1 = csrp + CSR_CAP;           // 4096
    unsigned short* w2p2 = w2p1 + 4096;              // 4096
    unsigned short* w1bf = w2p2 + 4096;              // 2,097,152 (4 MB)
    float* y1part = p;                               // alias over p..csrp (4.2 MB)

    const int* src = ei;
    const int* dst = ei + NE;

    // fused init + prepack (801 init blocks, 2 w2-pack blocks, 1024 w1-pack blocks)
    init_kernel<<<1827, 256, 0, stream>>>((int4*)csrp, (int4*)deg,
                                          (int4*)(p + (size_t)NN * HID),
                                          mp1_w2, mp2_w2, w2p1, w2p2,
                                          ro_w1, w1bf);

    hist_kernel<<<NE / 256, 256, 0, stream>>>(dst, deg);
    scan_kernel<<<1, 1024, 0, stream>>>(deg, offs, cur);
    scatter_kernel<<<(NE + NN) / 256, 256, 0, stream>>>(src, dst, cur, csrp);

    // layer 1 (2 waves x 8 nodes each -> NN*2/8 waves -> NN/16 blocks)
    pk_kernel<<<(NN * HID) / 256, 256, 0, stream>>>(x, mp1_w1, mp1_b1, p);
    edge_mfma_kernel<<<NN / 16, 256, 0, stream>>>(p, w2p1, mp1_b2, csrp, offs, cur, x1);
    // layer 2
    pk_kernel<<<(NN * HID) / 256, 256, 0, stream>>>(x1, mp2_w1, mp2_b1, p);
    edge_mfma_kernel<<<NN / 16, 256, 0, stream>>>(p, w2p2, mp2_b2, csrp, offs, cur, x1);

    // readout (p/deg/offs/cur/csrp dead; y1part reuses that region)
    ro1_kernel<<<128, 256, 0, stream>>>(x1, w1bf, y1part);
    ro2_kernel<<<256, 256, 0, stream>>>(y1part, ro_b1, ro_w2, ro_b2, out);
}

// Round 15
// 248.258 us; speedup vs baseline: 1.2909x; 1.1679x over previous
//
#include <hip/hip_runtime.h>
#include <hip/hip_bf16.h>
#include <cstdint>

#define NN 32768          // total nodes
#define NE 524288         // edges (before self-loops)
#define FEAT 256
#define HID 16
#define CSR_CAP (NE + 32 * NN)   // hard bound on padded CSR length (1,572,864)

typedef float f32x16 __attribute__((ext_vector_type(16)));
typedef float f32x8  __attribute__((ext_vector_type(8)));
typedef float f32x4  __attribute__((ext_vector_type(4)));
typedef float f32x2  __attribute__((ext_vector_type(2)));
typedef short s16x8  __attribute__((ext_vector_type(8)));
typedef int   i32x4  __attribute__((ext_vector_type(4)));
typedef int   i32x8  __attribute__((ext_vector_type(8)));

// ---------------- fused init + prepack ----------------
// blocks [0,801): csrp = 0xFF, deg = 0, dummy p-row = -1.7e38
// block 801: prepack layer-1 w2; block 802: layer-2 w2
// blocks [803, 803+1024): prepack ro_w1 -> single-bf16 B-fragments (4 MB)
__global__ __launch_bounds__(256) void init_kernel(int4* __restrict__ csrp16,
                                                   int4* __restrict__ deg16,
                                                   int4* __restrict__ dummy16,
                                                   const float* __restrict__ w2a,
                                                   const float* __restrict__ w2b,
                                                   unsigned short* __restrict__ pa,
                                                   unsigned short* __restrict__ pb,
                                                   const float* __restrict__ row1,
                                                   unsigned short* __restrict__ w1bf) {
    int b = blockIdx.x;
    if (b < 801) {
        int g = b * 256 + threadIdx.x;
        if (g < 196608) {
            int4 v = {-1, -1, -1, -1};
            csrp16[g] = v;
        } else if (g < 204800) {
            int4 v = {0, 0, 0, 0};
            deg16[g - 196608] = v;
        } else if (g < 204804) {
            int f = 0xFEFEFEFE;              // ~ -1.69e38
            int4 v = {f, f, f, f};
            dummy16[g - 204800] = v;
        }
    } else if (b < 803) {
        const float* w2 = (b == 801) ? w2a : w2b;
        unsigned short* w2p = (b == 801) ? pa : pb;
        #pragma unroll
        for (int rep = 0; rep < 2; ++rep) {
            int wk = threadIdx.x + rep * 256;
            int tt = wk >> 6, l = wk & 63;
            int c = l & 31, kh = l >> 5;
            s16x8 v;
            #pragma unroll
            for (int j = 0; j < 8; ++j) {
                float f = w2[(kh * 8 + j) * FEAT + tt * 32 + c];
                __hip_bfloat16 hb = __float2bfloat16(f);
                v[j] = __builtin_bit_cast(short, hb);
            }
            *(s16x8*)(w2p + (size_t)(tt * 64 + l) * 8) = v;
        }
    } else {
        // ro_w1 [32768][64] -> B-frag layout [ktile 0..2047][ntile 0..1][lane][8]
        int f = (b - 803) * 256 + threadIdx.x;   // 0..262143
        int ktile = f >> 7;
        int rem = f & 127;
        int nt = rem >> 6, l = rem & 63;
        int col = nt * 32 + (l & 31);
        int kb = ktile * 16 + (l >> 5) * 8;
        s16x8 v;
        #pragma unroll
        for (int j = 0; j < 8; ++j) {
            float w = row1[(size_t)(kb + j) * 64 + col];
            __hip_bfloat16 hb = __float2bfloat16(w);   // RNE single bf16
            v[j] = __builtin_bit_cast(short, hb);
        }
        *(s16x8*)(w1bf + (size_t)f * 8) = v;
    }
}

// ---------------- CSR build ----------------
__global__ void hist_kernel(const int* __restrict__ dst, int* __restrict__ deg) {
    int e = blockIdx.x * blockDim.x + threadIdx.x;
    if (e < NE) atomicAdd(&deg[dst[e]], 1);
}

// padded scan: each node's segment length = ceil((deg+1)/32)*32. int4 loads.
__global__ __launch_bounds__(1024) void scan_kernel(const int* __restrict__ deg,
                                                    int* __restrict__ offs,
                                                    int* __restrict__ cur) {
    __shared__ int sums[1024];
    int t = threadIdx.x;
    int base = t * 32;
    const int4* dp = (const int4*)deg + t * 8;
    int4 d4[8];
    #pragma unroll
    for (int i = 0; i < 8; ++i) d4[i] = dp[i];
    int local[32];
    int s = 0;
    #pragma unroll
    for (int i = 0; i < 8; ++i) {
        local[i * 4 + 0] = s; s += (d4[i].x + 32) & ~31;
        local[i * 4 + 1] = s; s += (d4[i].y + 32) & ~31;
        local[i * 4 + 2] = s; s += (d4[i].z + 32) & ~31;
        local[i * 4 + 3] = s; s += (d4[i].w + 32) & ~31;
    }
    sums[t] = s;
    __syncthreads();
    int own = s;
    for (int o = 1; o < 1024; o <<= 1) {
        int v = (t >= o) ? sums[t - o] : 0;
        __syncthreads();
        sums[t] += v;
        __syncthreads();
    }
    int ex = sums[t] - own;   // exclusive prefix
    #pragma unroll
    for (int i = 0; i < 32; ++i) {
        int v = ex + local[i];
        offs[base + i] = v;
        cur[base + i] = v;
    }
    if (t == 1023) offs[NN] = sums[1023];
}

// scatter resolved SRC node ids (ushort); pads remain 0xFFFF from init
__global__ void scatter_kernel(const int* __restrict__ src, const int* __restrict__ dst,
                               int* __restrict__ cur, unsigned short* __restrict__ csrp) {
    int g = blockIdx.x * blockDim.x + threadIdx.x;
    if (g < NE) {
        int pos = atomicAdd(&cur[dst[g]], 1);
        csrp[pos] = (unsigned short)src[g];
    } else if (g < NE + NN) {
        int i = g - NE;
        int pos = atomicAdd(&cur[i], 1);
        csrp[pos] = (unsigned short)i;    // self-loop: src == node
    }
}

// ---------------- p = x @ w1 + 0.5*b1  ([NN,16]) ----------------
__global__ __launch_bounds__(256) void pk_kernel(const float* __restrict__ x,
                                                 const float* __restrict__ w1,
                                                 const float* __restrict__ b1,
                                                 float* __restrict__ p) {
    __shared__ float w1s[16 * 260];   // transposed [j][k], pad to 260
    int t = threadIdx.x;
    for (int u = t; u < 4096; u += 256) {
        int k = u >> 4, j = u & 15;
        w1s[j * 260 + k] = w1[u];
    }
    __syncthreads();
    int gid = blockIdx.x * 256 + t;
    int i = gid >> 4, j = gid & 15;
    float acc = 0.5f * b1[j];
    const float* xr = x + (size_t)i * FEAT;
    const float* wr = w1s + j * 260;
    #pragma unroll 8
    for (int k = 0; k < 256; k += 4) {
        float4 xv = *(const float4*)(xr + k);
        float4 wv = *(const float4*)(wr + k);
        acc = fmaf(xv.x, wv.x, acc);
        acc = fmaf(xv.y, wv.y, acc);
        acc = fmaf(xv.z, wv.z, acc);
        acc = fmaf(xv.w, wv.w, acc);
    }
    p[gid] = acc;
}

// ---------------- edge MLP + aggregation via MFMA (r12/r13 validated) ----------------
__global__ __launch_bounds__(256) void edge_mfma_kernel(
    const float* __restrict__ p, const unsigned short* __restrict__ w2p,
    const float* __restrict__ b2, const unsigned short* __restrict__ csrp,
    const int* __restrict__ offs, const int* __restrict__ cur,
    float* __restrict__ out)
{
    int wid = threadIdx.x >> 6, lane = threadIdx.x & 63;
    int gw = __builtin_amdgcn_readfirstlane(blockIdx.x * 4 + wid);  // SGPR wave id
    int t0 = (gw & 1) * 4;                // this wave's col-tile base
    int nodeBase = (gw >> 1) * 8;         // 8 consecutive nodes per wave
    int r31 = lane & 31;          // A-row (edge slot) AND C-col
    int kh  = lane >> 5;          // k-half: k = kh*8 + j

    s16x8 B[4];
    #pragma unroll
    for (int tt = 0; tt < 4; ++tt)
        B[tt] = *(const s16x8*)(w2p + (size_t)((t0 + tt) * 64 + lane) * 8);

    float b2r[4], rb2[4];
    #pragma unroll
    for (int tt = 0; tt < 4; ++tt) {
        b2r[tt] = b2[(t0 + tt) * 32 + r31];
        rb2[tt] = fmaxf(b2r[tt], 0.f);
    }

    const int M16 = (int)0xFFFF0000;
    const i32x8 K8 = {M16, M16, M16, M16, M16, M16, M16, M16};

    #pragma unroll 1
    for (int u = 0; u < 8; ++u) {
        int node = nodeBase + u;          // SGPR

        f32x8 pd8;
        {
            float4 q0 = *(const float4*)(p + node * HID + kh * 8);
            float4 q1 = *(const float4*)(p + node * HID + kh * 8 + 4);
            pd8[0] = q0.x; pd8[1] = q0.y; pd8[2] = q0.z; pd8[3] = q0.w;
            pd8[4] = q1.x; pd8[5] = q1.y; pd8[6] = q1.z; pd8[7] = q1.w;
        }

        int rs = offs[node], re = offs[node + 1];
        int npad = re - cur[node];        // cur[node] = rs + (deg+1) after scatter

        float racc[4] = {0.f, 0.f, 0.f, 0.f};

        for (int pos = rs; pos < re; pos += 32) {
            int s = csrp[pos + r31];             // zero-extended ushort; pad = 65535
            int sp = min(s, NN);                 // pad -> dummy row (p[NN] = -1.7e38)
            const float* ps = p + sp * HID + kh * 8;
            float4 a0 = *(const float4*)ps;
            float4 a1 = *(const float4*)(ps + 4);
            f32x8 av = {a0.x, a0.y, a0.z, a0.w, a1.x, a1.y, a1.z, a1.w};

            f32x8 h8 = __builtin_elementwise_max(av + pd8, (f32x8){});
            i32x8 c8 = __builtin_bit_cast(i32x8, h8);
            i32x8 m8 = c8 & K8;
            f32x8 r8 = h8 - __builtin_bit_cast(f32x8, m8);
            i32x8 rc = __builtin_bit_cast(i32x8, r8);

            i32x4 hi4, lo4;
            hi4[0] = __builtin_amdgcn_perm(c8[1], c8[0], 0x07060302);
            hi4[1] = __builtin_amdgcn_perm(c8[3], c8[2], 0x07060302);
            hi4[2] = __builtin_amdgcn_perm(c8[5], c8[4], 0x07060302);
            hi4[3] = __builtin_amdgcn_perm(c8[7], c8[6], 0x07060302);
            lo4[0] = __builtin_amdgcn_perm(rc[1], rc[0], 0x07060302);
            lo4[1] = __builtin_amdgcn_perm(rc[3], rc[2], 0x07060302);
            lo4[2] = __builtin_amdgcn_perm(rc[5], rc[4], 0x07060302);
            lo4[3] = __builtin_amdgcn_perm(rc[7], rc[6], 0x07060302);

            s16x8 Ahi = __builtin_bit_cast(s16x8, hi4);
            s16x8 Alo = __builtin_bit_cast(s16x8, lo4);

            #pragma unroll
            for (int tt = 0; tt < 4; ++tt) {
                float bb = b2r[tt];
                f32x16 C = {bb,bb,bb,bb,bb,bb,bb,bb,bb,bb,bb,bb,bb,bb,bb,bb};
                C = __builtin_amdgcn_mfma_f32_32x32x16_bf16(Ahi, B[tt], C, 0, 0, 0);
                C = __builtin_amdgcn_mfma_f32_32x32x16_bf16(Alo, B[tt], C, 0, 0, 0);
                C = __builtin_elementwise_max(C, (f32x16){});
                f32x8 s8 = __builtin_shufflevector(C, C, 0, 1, 2, 3, 4, 5, 6, 7)
                         + __builtin_shufflevector(C, C, 8, 9, 10, 11, 12, 13, 14, 15);
                f32x4 s4 = __builtin_shufflevector(s8, s8, 0, 1, 2, 3)
                         + __builtin_shufflevector(s8, s8, 4, 5, 6, 7);
                f32x2 s2 = __builtin_shufflevector(s4, s4, 0, 1)
                         + __builtin_shufflevector(s4, s4, 2, 3);
                racc[tt] += s2[0] + s2[1];
                __builtin_amdgcn_sched_barrier(0);   // bound C-tile liveness to 1
            }
        }

        #pragma unroll
        for (int tt = 0; tt < 4; ++tt) {
            racc[tt] += __shfl_xor(racc[tt], 32, 64);    // combine row-halves
            racc[tt] -= (float)npad * rb2[tt];           // cancel pad rows
        }

        float* ob = out + (size_t)node * FEAT + r31;
        if (kh == 0) {
            ob[(t0 + 0) * 32] = racc[0];
            ob[(t0 + 1) * 32] = racc[1];
        } else {
            ob[(t0 + 2) * 32] = racc[2];
            ob[(t0 + 3) * 32] = racc[3];
        }
    }
}

// ---------------- readout GEMM1 via MFMA: y1part[ks][256][64] ----------------
__global__ __launch_bounds__(256) void ro1_kernel(const float* __restrict__ y,
                                                  const unsigned short* __restrict__ w1bf,
                                                  float* __restrict__ y1part) {
    int wid = threadIdx.x >> 6, lane = threadIdx.x & 63;
    int gw = blockIdx.x * 4 + wid;       // 0..511
    int mt = gw >> 6;                    // 0..7
    int ks = gw & 63;                    // 0..63
    int r31 = lane & 31;
    int kh  = lane >> 5;

    const float* yr = y + (size_t)(mt * 32 + r31) * 32768 + kh * 8;

    const int M16 = (int)0xFFFF0000;
    const i32x8 K8 = {M16, M16, M16, M16, M16, M16, M16, M16};

    f32x16 C0 = {}, C1 = {};

    #pragma unroll 4
    for (int kt = 0; kt < 32; ++kt) {
        int ktile = ks * 32 + kt;
        int kb = ktile * 16;

        float4 a0 = *(const float4*)(yr + kb);
        float4 a1 = *(const float4*)(yr + kb + 4);
        f32x8 av = {a0.x, a0.y, a0.z, a0.w, a1.x, a1.y, a1.z, a1.w};

        i32x8 c8 = __builtin_bit_cast(i32x8, av);
        i32x8 m8 = c8 & K8;
        f32x8 r8 = av - __builtin_bit_cast(f32x8, m8);
        i32x8 rc = __builtin_bit_cast(i32x8, r8);

        i32x4 hi4, lo4;
        hi4[0] = __builtin_amdgcn_perm(c8[1], c8[0], 0x07060302);
        hi4[1] = __builtin_amdgcn_perm(c8[3], c8[2], 0x07060302);
        hi4[2] = __builtin_amdgcn_perm(c8[5], c8[4], 0x07060302);
        hi4[3] = __builtin_amdgcn_perm(c8[7], c8[6], 0x07060302);
        lo4[0] = __builtin_amdgcn_perm(rc[1], rc[0], 0x07060302);
        lo4[1] = __builtin_amdgcn_perm(rc[3], rc[2], 0x07060302);
        lo4[2] = __builtin_amdgcn_perm(rc[5], rc[4], 0x07060302);
        lo4[3] = __builtin_amdgcn_perm(rc[7], rc[6], 0x07060302);

        s16x8 Ahi = __builtin_bit_cast(s16x8, hi4);
        s16x8 Alo = __builtin_bit_cast(s16x8, lo4);

        s16x8 B0 = *(const s16x8*)(w1bf + ((size_t)(ktile * 2 + 0) * 64 + lane) * 8);
        s16x8 B1 = *(const s16x8*)(w1bf + ((size_t)(ktile * 2 + 1) * 64 + lane) * 8);

        C0 = __builtin_amdgcn_mfma_f32_32x32x16_bf16(Ahi, B0, C0, 0, 0, 0);
        C0 = __builtin_amdgcn_mfma_f32_32x32x16_bf16(Alo, B0, C0, 0, 0, 0);
        C1 = __builtin_amdgcn_mfma_f32_32x32x16_bf16(Ahi, B1, C1, 0, 0, 0);
        C1 = __builtin_amdgcn_mfma_f32_32x32x16_bf16(Alo, B1, C1, 0, 0, 0);
    }

    // C layout: col = lane&31, row = (reg&3) + 8*(reg>>2) + 4*(lane>>5)
    float* yp = y1part + (size_t)ks * 16384 + (size_t)(mt * 32) * 64;
    #pragma unroll
    for (int reg = 0; reg < 16; ++reg) {
        int row = (reg & 3) + 8 * (reg >> 2) + 4 * kh;
        yp[row * 64 + r31]      = C0[reg];
        yp[row * 64 + 32 + r31] = C1[reg];
    }
}

// ---------------- reduce 64 partials + bias + relu -> y1[16384] ----------------
// Done ONCE (r14 lesson: fusing this into ro2 redid it 64x per m-tile).
__global__ void relub_kernel(const float* __restrict__ y1part, const float* __restrict__ b1,
                             float* __restrict__ y1) {
    int i = blockIdx.x * 256 + threadIdx.x;
    float s = b1[i & 63];
    #pragma unroll 8
    for (int kb = 0; kb < 64; ++kb) s += y1part[(size_t)kb * 16384 + i];
    y1[i] = fmaxf(s, 0.f);
}

// ---------------- readout GEMM2: out = relu(y1[256,64] @ w2[64,16384] + b2) ----------------
// 512 blocks (8 m-tiles of 32 x 64 n-tiles) -> 2 blocks/CU for TLP.
__global__ __launch_bounds__(256) void ro2_kernel(const float* __restrict__ y1,
                                                  const float* __restrict__ w2,
                                                  const float* __restrict__ b2,
                                                  float* __restrict__ out) {
    __shared__ float yls[32 * 68];
    int mt = blockIdx.x >> 6;            // 8 m-tiles of 32
    int nt = blockIdx.x & 63;            // 64 n-tiles of 256
    int t = threadIdx.x;
    for (int u = t; u < 2048; u += 256) {
        int row = u >> 6, col = u & 63;
        yls[row * 68 + col] = y1[(mt * 32 + row) * 64 + col];   // coalesced
    }
    __syncthreads();

    int n = nt * 256 + t;
    float w2r[64];
    #pragma unroll
    for (int jj = 0; jj < 64; ++jj) w2r[jj] = w2[(size_t)jj * 16384 + n];
    float bb = b2[n];
    for (int m = 0; m < 32; ++m) {
        float acc = bb;
        const float* yr = &yls[m * 68];
        #pragma unroll
        for (int jj = 0; jj < 64; jj += 4) {
            float4 yv = *(const float4*)(yr + jj);
            acc = fmaf(yv.x, w2r[jj],     acc);
            acc = fmaf(yv.y, w2r[jj + 1], acc);
            acc = fmaf(yv.z, w2r[jj + 2], acc);
            acc = fmaf(yv.w, w2r[jj + 3], acc);
        }
        out[(size_t)(mt * 32 + m) * 16384 + n] = fmaxf(acc, 0.f);
    }
}

extern "C" void kernel_launch(void* const* d_in, const int* in_sizes, int n_in,
                              void* d_out, int out_size, void* d_ws, size_t ws_size,
                              hipStream_t stream) {
    (void)in_sizes; (void)n_in; (void)out_size; (void)ws_size;
    const float* x      = (const float*)d_in[0];
    const int*   ei     = (const int*)d_in[1];     // [2, NE] : row0 src, row1 dst
    const float* mp1_w1 = (const float*)d_in[2];
    const float* mp1_b1 = (const float*)d_in[3];
    const float* mp1_w2 = (const float*)d_in[4];
    const float* mp1_b2 = (const float*)d_in[5];
    const float* mp2_w1 = (const float*)d_in[6];
    const float* mp2_b1 = (const float*)d_in[7];
    const float* mp2_w2 = (const float*)d_in[8];
    const float* mp2_b2 = (const float*)d_in[9];
    const float* ro_w1  = (const float*)d_in[10];
    const float* ro_b1  = (const float*)d_in[11];
    const float* ro_w2  = (const float*)d_in[12];
    const float* ro_b2  = (const float*)d_in[13];
    float* out = (float*)d_out;

    // workspace carve-up (~45.4 MB). [p..csrp] is a contiguous 5.6 MB region
    // that y1part (64*16384 floats = 4.2 MB) aliases after the edge layers.
    float* x1     = (float*)d_ws;                    // NN*256
    float* p      = x1 + (size_t)NN * FEAT;          // (NN+1)*16 = 524304 floats
    int*   deg    = (int*)(p + 524304);              // NN
    int*   offs   = deg + NN;                        // NN+1
    int*   cur    = offs + NN + 1;                   // NN (+3 pad for 16B align)
    unsigned short* csrp = (unsigned short*)(cur + NN + 3);  // CSR_CAP (16B aligned)
    unsigned short* w2p1 = csrp + CSR_CAP;           // 4096
    unsigned short* w2p2 = w2p1 + 4096;              // 4096
    unsigned short* w1bf = w2p2 + 4096;              // 2,097,152 (4 MB)
    float* y1     = (float*)(w1bf + 2097152);        // 16384 floats (64 KB)
    float* y1part = p;                               // alias over p..csrp (4.2 MB)

    const int* src = ei;
    const int* dst = ei + NE;

    // fused init + prepack (801 init blocks, 2 w2-pack blocks, 1024 w1-pack blocks)
    init_kernel<<<1827, 256, 0, stream>>>((int4*)csrp, (int4*)deg,
                                          (int4*)(p + (size_t)NN * HID),
                                          mp1_w2, mp2_w2, w2p1, w2p2,
                                          ro_w1, w1bf);

    hist_kernel<<<NE / 256, 256, 0, stream>>>(dst, deg);
    scan_kernel<<<1, 1024, 0, stream>>>(deg, offs, cur);
    scatter_kernel<<<(NE + NN) / 256, 256, 0, stream>>>(src, dst, cur, csrp);

    // layer 1 (2 waves x 8 nodes each -> NN*2/8 waves -> NN/16 blocks)
    pk_kernel<<<(NN * HID) / 256, 256, 0, stream>>>(x, mp1_w1, mp1_b1, p);
    edge_mfma_kernel<<<NN / 16, 256, 0, stream>>>(p, w2p1, mp1_b2, csrp, offs, cur, x1);
    // layer 2
    pk_kernel<<<(NN * HID) / 256, 256, 0, stream>>>(x1, mp2_w1, mp2_b1, p);
    edge_mfma_kernel<<<NN / 16, 256, 0, stream>>>(p, w2p2, mp2_b2, csrp, offs, cur, x1);

    // readout (p/deg/offs/cur/csrp dead; y1part reuses that region)
    ro1_kernel<<<128, 256, 0, stream>>>(x1, w1bf, y1part);
    relub_kernel<<<64, 256, 0, stream>>>(y1part, ro_b1, y1);
    ro2_kernel<<<512, 256, 0, stream>>>(y1, ro_w2, ro_b2, out);
}

// Round 16
// 235.384 us; speedup vs baseline: 1.3615x; 1.0547x over previous
//
#include <hip/hip_runtime.h>
#include <hip/hip_bf16.h>
#include <cstdint>

#define NN 32768          // total nodes
#define NE 524288         // edges (before self-loops)
#define FEAT 256
#define HID 16
#define CSR_CAP (NE + 32 * NN)   // hard bound on padded CSR length (1,572,864)

typedef float f32x16 __attribute__((ext_vector_type(16)));
typedef short s16x8  __attribute__((ext_vector_type(8)));
typedef int   i32x4  __attribute__((ext_vector_type(4)));

// ---------------- fused init + prepack ----------------
// blocks [0,32): deg = 0; block 32: dummy p-row = -1.7e38
// blocks 33,34: prepack layer-1/2 w2 -> MFMA B-fragments
// blocks [35, 35+1024): prepack ro_w1 -> single-bf16 B-fragments (4 MB)
// (csrp is NOT initialized: pads are detected via pos >= cur[node] in edge)
__global__ __launch_bounds__(256) void init_kernel(int4* __restrict__ deg16,
                                                   int4* __restrict__ dummy16,
                                                   const float* __restrict__ w2a,
                                                   const float* __restrict__ w2b,
                                                   unsigned short* __restrict__ pa,
                                                   unsigned short* __restrict__ pb,
                                                   const float* __restrict__ row1,
                                                   unsigned short* __restrict__ w1bf) {
    int b = blockIdx.x;
    if (b < 32) {
        int4 v = {0, 0, 0, 0};
        deg16[b * 256 + threadIdx.x] = v;
    } else if (b == 32) {
        if (threadIdx.x < 4) {
            int f = 0xFEFEFEFE;              // ~ -1.69e38
            int4 v = {f, f, f, f};
            dummy16[threadIdx.x] = v;
        }
    } else if (b < 35) {
        const float* w2 = (b == 33) ? w2a : w2b;
        unsigned short* w2p = (b == 33) ? pa : pb;
        #pragma unroll
        for (int rep = 0; rep < 2; ++rep) {
            int wk = threadIdx.x + rep * 256;
            int tt = wk >> 6, l = wk & 63;
            int c = l & 31, kh = l >> 5;
            s16x8 v;
            #pragma unroll
            for (int j = 0; j < 8; ++j) {
                float f = w2[(kh * 8 + j) * FEAT + tt * 32 + c];
                __hip_bfloat16 hb = __float2bfloat16(f);
                v[j] = __builtin_bit_cast(short, hb);
            }
            *(s16x8*)(w2p + (size_t)(tt * 64 + l) * 8) = v;
        }
    } else {
        // ro_w1 [32768][64] -> B-frag layout [ktile 0..2047][ntile 0..1][lane][8]
        int f = (b - 35) * 256 + threadIdx.x;    // 0..262143
        int ktile = f >> 7;
        int rem = f & 127;
        int nt = rem >> 6, l = rem & 63;
        int col = nt * 32 + (l & 31);
        int kb = ktile * 16 + (l >> 5) * 8;
        s16x8 v;
        #pragma unroll
        for (int j = 0; j < 8; ++j) {
            float w = row1[(size_t)(kb + j) * 64 + col];
            __hip_bfloat16 hb = __float2bfloat16(w);   // RNE single bf16
            v[j] = __builtin_bit_cast(short, hb);
        }
        *(s16x8*)(w1bf + (size_t)f * 8) = v;
    }
}

// ---------------- CSR build ----------------
__global__ void hist_kernel(const int* __restrict__ dst, int* __restrict__ deg) {
    int e = blockIdx.x * blockDim.x + threadIdx.x;
    if (e < NE) atomicAdd(&deg[dst[e]], 1);
}

// padded scan: each node's segment length = ceil((deg+1)/32)*32. int4 loads.
__global__ __launch_bounds__(1024) void scan_kernel(const int* __restrict__ deg,
                                                    int* __restrict__ offs,
                                                    int* __restrict__ cur) {
    __shared__ int sums[1024];
    int t = threadIdx.x;
    int base = t * 32;
    const int4* dp = (const int4*)deg + t * 8;
    int4 d4[8];
    #pragma unroll
    for (int i = 0; i < 8; ++i) d4[i] = dp[i];
    int local[32];
    int s = 0;
    #pragma unroll
    for (int i = 0; i < 8; ++i) {
        local[i * 4 + 0] = s; s += (d4[i].x + 32) & ~31;
        local[i * 4 + 1] = s; s += (d4[i].y + 32) & ~31;
        local[i * 4 + 2] = s; s += (d4[i].z + 32) & ~31;
        local[i * 4 + 3] = s; s += (d4[i].w + 32) & ~31;
    }
    sums[t] = s;
    __syncthreads();
    int own = s;
    for (int o = 1; o < 1024; o <<= 1) {
        int v = (t >= o) ? sums[t - o] : 0;
        __syncthreads();
        sums[t] += v;
        __syncthreads();
    }
    int ex = sums[t] - own;   // exclusive prefix
    #pragma unroll
    for (int i = 0; i < 32; ++i) {
        int v = ex + local[i];
        offs[base + i] = v;
        cur[base + i] = v;
    }
    if (t == 1023) offs[NN] = sums[1023];
}

// ---------------- fused scatter (CSR fill) ∥ pk layer-1 ----------------
// blocks [0, 2176): scatter resolved SRC ids (ushort) into csrp.
// blocks [2176, 4224): pk1 = x @ w1 + 0.5*b1 (independent work; overlaps the
// atomic-latency-bound scatter with compute).
__global__ __launch_bounds__(256) void scatter_pk_kernel(
    const int* __restrict__ src, const int* __restrict__ dst,
    int* __restrict__ cur, unsigned short* __restrict__ csrp,
    const float* __restrict__ x, const float* __restrict__ w1,
    const float* __restrict__ b1, float* __restrict__ p)
{
    __shared__ float w1s[16 * 260];
    int b = blockIdx.x;
    if (b < (NE + NN) / 256) {
        int g = b * 256 + threadIdx.x;
        if (g < NE) {
            int pos = atomicAdd(&cur[dst[g]], 1);
            csrp[pos] = (unsigned short)src[g];
        } else {
            int i = g - NE;
            int pos = atomicAdd(&cur[i], 1);
            csrp[pos] = (unsigned short)i;    // self-loop: src == node
        }
    } else {
        int t = threadIdx.x;
        for (int u = t; u < 4096; u += 256) {
            int k = u >> 4, j = u & 15;
            w1s[j * 260 + k] = w1[u];
        }
        __syncthreads();
        int gid = (b - (NE + NN) / 256) * 256 + t;
        int i = gid >> 4, j = gid & 15;
        float acc = 0.5f * b1[j];
        const float* xr = x + (size_t)i * FEAT;
        const float* wr = w1s + j * 260;
        #pragma unroll 8
        for (int k = 0; k < 256; k += 4) {
            float4 xv = *(const float4*)(xr + k);
            float4 wv = *(const float4*)(wr + k);
            acc = fmaf(xv.x, wv.x, acc);
            acc = fmaf(xv.y, wv.y, acc);
            acc = fmaf(xv.z, wv.z, acc);
            acc = fmaf(xv.w, wv.w, acc);
        }
        p[gid] = acc;
    }
}

// ---------------- p = x @ w1 + 0.5*b1  ([NN,16]) (standalone, layer 2) ----------------
__global__ __launch_bounds__(256) void pk_kernel(const float* __restrict__ x,
                                                 const float* __restrict__ w1,
                                                 const float* __restrict__ b1,
                                                 float* __restrict__ p) {
    __shared__ float w1s[16 * 260];   // transposed [j][k], pad to 260
    int t = threadIdx.x;
    for (int u = t; u < 4096; u += 256) {
        int k = u >> 4, j = u & 15;
        w1s[j * 260 + k] = w1[u];
    }
    __syncthreads();
    int gid = blockIdx.x * 256 + t;
    int i = gid >> 4, j = gid & 15;
    float acc = 0.5f * b1[j];
    const float* xr = x + (size_t)i * FEAT;
    const float* wr = w1s + j * 260;
    #pragma unroll 8
    for (int k = 0; k < 256; k += 4) {
        float4 xv = *(const float4*)(xr + k);
        float4 wv = *(const float4*)(wr + k);
        acc = fmaf(xv.x, wv.x, acc);
        acc = fmaf(xv.y, wv.y, acc);
        acc = fmaf(xv.z, wv.z, acc);
        acc = fmaf(xv.w, wv.w, acc);
    }
    p[gid] = acc;
}

// ---------------- edge MLP + aggregation via MFMA ----------------
// r12 scalar inner loop (measured-best: VGPR 48, occ 37%, 48.6 us — the r13
// ext_vector epilogue regressed to VGPR 72 / 52.4 us and is reverted).
// Pads detected via (pos + r31) >= cur[node] -> dummy row p[NN] = -1.7e38 ->
// h = 0 (no csrp sentinel, so no csrp memset needed).
// C preloaded with bias; pad rows contribute relu(b2), cancelled via npad.
// sched_barrier(0) per tt bounds C-tile liveness to 1.
// NO min-waves launch_bounds cap (r6: cap below demand => 2.3 GB scratch spill).
__global__ __launch_bounds__(256) void edge_mfma_kernel(
    const float* __restrict__ p, const unsigned short* __restrict__ w2p,
    const float* __restrict__ b2, const unsigned short* __restrict__ csrp,
    const int* __restrict__ offs, const int* __restrict__ cur,
    float* __restrict__ out)
{
    int wid = threadIdx.x >> 6, lane = threadIdx.x & 63;
    int gw = __builtin_amdgcn_readfirstlane(blockIdx.x * 4 + wid);  // SGPR wave id
    int t0 = (gw & 1) * 4;                // this wave's col-tile base
    int nodeBase = (gw >> 1) * 8;         // 8 consecutive nodes per wave
    int r31 = lane & 31;          // A-row (edge slot) AND C-col
    int kh  = lane >> 5;          // k-half: k = kh*8 + j

    s16x8 B[4];
    #pragma unroll
    for (int tt = 0; tt < 4; ++tt)
        B[tt] = *(const s16x8*)(w2p + (size_t)((t0 + tt) * 64 + lane) * 8);

    float b2r[4], rb2[4];
    #pragma unroll
    for (int tt = 0; tt < 4; ++tt) {
        b2r[tt] = b2[(t0 + tt) * 32 + r31];
        rb2[tt] = fmaxf(b2r[tt], 0.f);
    }

    #pragma unroll 1
    for (int u = 0; u < 8; ++u) {
        int node = nodeBase + u;          // SGPR

        float pd[8];
        {
            float4 q0 = *(const float4*)(p + node * HID + kh * 8);
            float4 q1 = *(const float4*)(p + node * HID + kh * 8 + 4);
            pd[0] = q0.x; pd[1] = q0.y; pd[2] = q0.z; pd[3] = q0.w;
            pd[4] = q1.x; pd[5] = q1.y; pd[6] = q1.z; pd[7] = q1.w;
        }

        int rs = offs[node], re = offs[node + 1];
        int curn = cur[node];             // rs + (deg+1) after scatter
        int npad = re - curn;

        float racc[4] = {0.f, 0.f, 0.f, 0.f};

        for (int pos = rs; pos < re; pos += 32) {
            int idx = pos + r31;
            int s = csrp[idx];                   // garbage beyond curn: masked below
            int sp = (idx < curn) ? s : NN;      // pad -> dummy row (p[NN] = -1.7e38)
            const float* ps = p + sp * HID + kh * 8;
            float4 a0 = *(const float4*)ps;
            float4 a1 = *(const float4*)(ps + 4);
            float h0 = fmaxf(a0.x + pd[0], 0.f);
            float h1 = fmaxf(a0.y + pd[1], 0.f);
            float h2 = fmaxf(a0.z + pd[2], 0.f);
            float h3 = fmaxf(a0.w + pd[3], 0.f);
            float h4 = fmaxf(a1.x + pd[4], 0.f);
            float h5 = fmaxf(a1.y + pd[5], 0.f);
            float h6 = fmaxf(a1.z + pd[6], 0.f);
            float h7 = fmaxf(a1.w + pd[7], 0.f);

            int c0 = __float_as_int(h0), c1 = __float_as_int(h1);
            int c2 = __float_as_int(h2), c3 = __float_as_int(h3);
            int c4 = __float_as_int(h4), c5 = __float_as_int(h5);
            int c6 = __float_as_int(h6), c7 = __float_as_int(h7);

            i32x4 hi4, lo4;
            hi4[0] = __builtin_amdgcn_perm(c1, c0, 0x07060302);
            hi4[1] = __builtin_amdgcn_perm(c3, c2, 0x07060302);
            hi4[2] = __builtin_amdgcn_perm(c5, c4, 0x07060302);
            hi4[3] = __builtin_amdgcn_perm(c7, c6, 0x07060302);

            float r0 = h0 - __int_as_float(c0 & 0xFFFF0000);
            float r1 = h1 - __int_as_float(c1 & 0xFFFF0000);
            float r2 = h2 - __int_as_float(c2 & 0xFFFF0000);
            float r3 = h3 - __int_as_float(c3 & 0xFFFF0000);
            float r4 = h4 - __int_as_float(c4 & 0xFFFF0000);
            float r5 = h5 - __int_as_float(c5 & 0xFFFF0000);
            float r6 = h6 - __int_as_float(c6 & 0xFFFF0000);
            float r7 = h7 - __int_as_float(c7 & 0xFFFF0000);
            lo4[0] = __builtin_amdgcn_perm(__float_as_int(r1), __float_as_int(r0), 0x07060302);
            lo4[1] = __builtin_amdgcn_perm(__float_as_int(r3), __float_as_int(r2), 0x07060302);
            lo4[2] = __builtin_amdgcn_perm(__float_as_int(r5), __float_as_int(r4), 0x07060302);
            lo4[3] = __builtin_amdgcn_perm(__float_as_int(r7), __float_as_int(r6), 0x07060302);

            s16x8 Ahi = __builtin_bit_cast(s16x8, hi4);
            s16x8 Alo = __builtin_bit_cast(s16x8, lo4);

            #pragma unroll
            for (int tt = 0; tt < 4; ++tt) {
                float bb = b2r[tt];
                f32x16 C = {bb,bb,bb,bb,bb,bb,bb,bb,bb,bb,bb,bb,bb,bb,bb,bb};
                C = __builtin_amdgcn_mfma_f32_32x32x16_bf16(Ahi, B[tt], C, 0, 0, 0);
                C = __builtin_amdgcn_mfma_f32_32x32x16_bf16(Alo, B[tt], C, 0, 0, 0);
                float s0 = fmaxf(C[0], 0.f)  + fmaxf(C[1], 0.f);
                float s1 = fmaxf(C[2], 0.f)  + fmaxf(C[3], 0.f);
                float s2 = fmaxf(C[4], 0.f)  + fmaxf(C[5], 0.f);
                float s3 = fmaxf(C[6], 0.f)  + fmaxf(C[7], 0.f);
                float s4 = fmaxf(C[8], 0.f)  + fmaxf(C[9], 0.f);
                float s5 = fmaxf(C[10], 0.f) + fmaxf(C[11], 0.f);
                float s6 = fmaxf(C[12], 0.f) + fmaxf(C[13], 0.f);
                float s7 = fmaxf(C[14], 0.f) + fmaxf(C[15], 0.f);
                racc[tt] += ((s0 + s1) + (s2 + s3)) + ((s4 + s5) + (s6 + s7));
                __builtin_amdgcn_sched_barrier(0);   // bound C-tile liveness to 1
            }
        }

        #pragma unroll
        for (int tt = 0; tt < 4; ++tt) {
            racc[tt] += __shfl_xor(racc[tt], 32, 64);    // combine row-halves
            racc[tt] -= (float)npad * rb2[tt];           // cancel pad rows
        }

        float* ob = out + (size_t)node * FEAT + r31;
        if (kh == 0) {
            ob[(t0 + 0) * 32] = racc[0];
            ob[(t0 + 1) * 32] = racc[1];
        } else {
            ob[(t0 + 2) * 32] = racc[2];
            ob[(t0 + 3) * 32] = racc[3];
        }
    }
}

// ---------------- readout GEMM1 via MFMA: y1part[ks][256][64] ----------------
__global__ __launch_bounds__(256) void ro1_kernel(const float* __restrict__ y,
                                                  const unsigned short* __restrict__ w1bf,
                                                  float* __restrict__ y1part) {
    int wid = threadIdx.x >> 6, lane = threadIdx.x & 63;
    int gw = blockIdx.x * 4 + wid;       // 0..511
    int mt = gw >> 6;                    // 0..7
    int ks = gw & 63;                    // 0..63
    int r31 = lane & 31;
    int kh  = lane >> 5;

    const float* yr = y + (size_t)(mt * 32 + r31) * 32768 + kh * 8;

    f32x16 C0 = {}, C1 = {};

    #pragma unroll 4
    for (int kt = 0; kt < 32; ++kt) {
        int ktile = ks * 32 + kt;
        int kb = ktile * 16;

        float4 a0 = *(const float4*)(yr + kb);
        float4 a1 = *(const float4*)(yr + kb + 4);
        float h0 = a0.x, h1 = a0.y, h2 = a0.z, h3 = a0.w;
        float h4 = a1.x, h5 = a1.y, h6 = a1.z, h7 = a1.w;

        int c0 = __float_as_int(h0), c1 = __float_as_int(h1);
        int c2 = __float_as_int(h2), c3 = __float_as_int(h3);
        int c4 = __float_as_int(h4), c5 = __float_as_int(h5);
        int c6 = __float_as_int(h6), c7 = __float_as_int(h7);

        i32x4 hi4, lo4;
        hi4[0] = __builtin_amdgcn_perm(c1, c0, 0x07060302);
        hi4[1] = __builtin_amdgcn_perm(c3, c2, 0x07060302);
        hi4[2] = __builtin_amdgcn_perm(c5, c4, 0x07060302);
        hi4[3] = __builtin_amdgcn_perm(c7, c6, 0x07060302);

        float r0 = h0 - __int_as_float(c0 & 0xFFFF0000);
        float r1 = h1 - __int_as_float(c1 & 0xFFFF0000);
        float r2 = h2 - __int_as_float(c2 & 0xFFFF0000);
        float r3 = h3 - __int_as_float(c3 & 0xFFFF0000);
        float r4 = h4 - __int_as_float(c4 & 0xFFFF0000);
        float r5 = h5 - __int_as_float(c5 & 0xFFFF0000);
        float r6 = h6 - __int_as_float(c6 & 0xFFFF0000);
        float r7 = h7 - __int_as_float(c7 & 0xFFFF0000);
        lo4[0] = __builtin_amdgcn_perm(__float_as_int(r1), __float_as_int(r0), 0x07060302);
        lo4[1] = __builtin_amdgcn_perm(__float_as_int(r3), __float_as_int(r2), 0x07060302);
        lo4[2] = __builtin_amdgcn_perm(__float_as_int(r5), __float_as_int(r4), 0x07060302);
        lo4[3] = __builtin_amdgcn_perm(__float_as_int(r7), __float_as_int(r6), 0x07060302);

        s16x8 Ahi = __builtin_bit_cast(s16x8, hi4);
        s16x8 Alo = __builtin_bit_cast(s16x8, lo4);

        s16x8 B0 = *(const s16x8*)(w1bf + ((size_t)(ktile * 2 + 0) * 64 + lane) * 8);
        s16x8 B1 = *(const s16x8*)(w1bf + ((size_t)(ktile * 2 + 1) * 64 + lane) * 8);

        C0 = __builtin_amdgcn_mfma_f32_32x32x16_bf16(Ahi, B0, C0, 0, 0, 0);
        C0 = __builtin_amdgcn_mfma_f32_32x32x16_bf16(Alo, B0, C0, 0, 0, 0);
        C1 = __builtin_amdgcn_mfma_f32_32x32x16_bf16(Ahi, B1, C1, 0, 0, 0);
        C1 = __builtin_amdgcn_mfma_f32_32x32x16_bf16(Alo, B1, C1, 0, 0, 0);
    }

    // C layout: col = lane&31, row = (reg&3) + 8*(reg>>2) + 4*(lane>>5)
    float* yp = y1part + (size_t)ks * 16384 + (size_t)(mt * 32) * 64;
    #pragma unroll
    for (int reg = 0; reg < 16; ++reg) {
        int row = (reg & 3) + 8 * (reg >> 2) + 4 * kh;
        yp[row * 64 + r31]      = C0[reg];
        yp[row * 64 + 32 + r31] = C1[reg];
    }
}

// ---------------- reduce 64 partials + bias + relu -> y1[16384] ----------------
__global__ void relub_kernel(const float* __restrict__ y1part, const float* __restrict__ b1,
                             float* __restrict__ y1) {
    int i = blockIdx.x * 256 + threadIdx.x;
    float s = b1[i & 63];
    #pragma unroll 8
    for (int kb = 0; kb < 64; ++kb) s += y1part[(size_t)kb * 16384 + i];
    y1[i] = fmaxf(s, 0.f);
}

// ---------------- readout GEMM2: out = relu(y1[256,64] @ w2[64,16384] + b2) ----------------
__global__ __launch_bounds__(256) void ro2_kernel(const float* __restrict__ y1,
                                                  const float* __restrict__ w2,
                                                  const float* __restrict__ b2,
                                                  float* __restrict__ out) {
    __shared__ float yls[32 * 68];
    int mt = blockIdx.x >> 6;            // 8 m-tiles of 32
    int nt = blockIdx.x & 63;            // 64 n-tiles of 256
    int t = threadIdx.x;
    for (int u = t; u < 2048; u += 256) {
        int row = u >> 6, col = u & 63;
        yls[row * 68 + col] = y1[(mt * 32 + row) * 64 + col];   // coalesced
    }
    __syncthreads();

    int n = nt * 256 + t;
    float w2r[64];
    #pragma unroll
    for (int jj = 0; jj < 64; ++jj) w2r[jj] = w2[(size_t)jj * 16384 + n];
    float bb = b2[n];
    for (int m = 0; m < 32; ++m) {
        float acc = bb;
        const float* yr = &yls[m * 68];
        #pragma unroll
        for (int jj = 0; jj < 64; jj += 4) {
            float4 yv = *(const float4*)(yr + jj);
            acc = fmaf(yv.x, w2r[jj],     acc);
            acc = fmaf(yv.y, w2r[jj + 1], acc);
            acc = fmaf(yv.z, w2r[jj + 2], acc);
            acc = fmaf(yv.w, w2r[jj + 3], acc);
        }
        out[(size_t)(mt * 32 + m) * 16384 + n] = fmaxf(acc, 0.f);
    }
}

extern "C" void kernel_launch(void* const* d_in, const int* in_sizes, int n_in,
                              void* d_out, int out_size, void* d_ws, size_t ws_size,
                              hipStream_t stream) {
    (void)in_sizes; (void)n_in; (void)out_size; (void)ws_size;
    const float* x      = (const float*)d_in[0];
    const int*   ei     = (const int*)d_in[1];     // [2, NE] : row0 src, row1 dst
    const float* mp1_w1 = (const float*)d_in[2];
    const float* mp1_b1 = (const float*)d_in[3];
    const float* mp1_w2 = (const float*)d_in[4];
    const float* mp1_b2 = (const float*)d_in[5];
    const float* mp2_w1 = (const float*)d_in[6];
    const float* mp2_b1 = (const float*)d_in[7];
    const float* mp2_w2 = (const float*)d_in[8];
    const float* mp2_b2 = (const float*)d_in[9];
    const float* ro_w1  = (const float*)d_in[10];
    const float* ro_b1  = (const float*)d_in[11];
    const float* ro_w2  = (const float*)d_in[12];
    const float* ro_b2  = (const float*)d_in[13];
    float* out = (float*)d_out;

    // workspace carve-up (~45.4 MB). [p..csrp] is a contiguous 5.6 MB region
    // that y1part (64*16384 floats = 4.2 MB) aliases after the edge layers.
    float* x1     = (float*)d_ws;                    // NN*256
    float* p      = x1 + (size_t)NN * FEAT;          // (NN+1)*16 = 524304 floats
    int*   deg    = (int*)(p + 524304);              // NN
    int*   offs   = deg + NN;                        // NN+1
    int*   cur    = offs + NN + 1;                   // NN (+3 pad for 16B align)
    unsigned short* csrp = (unsigned short*)(cur + NN + 3);  // CSR_CAP (16B aligned)
    unsigned short* w2p1 = csrp + CSR_CAP;           // 4096
    unsigned short* w2p2 = w2p1 + 4096;              // 4096
    unsigned short* w1bf = w2p2 + 4096;              // 2,097,152 (4 MB)
    float* y1     = (float*)(w1bf + 2097152);        // 16384 floats (64 KB)
    float* y1part = p;                               // alias over p..csrp (4.2 MB)

    const int* src = ei;
    const int* dst = ei + NE;

    // fused init + prepack (32 deg blocks + 1 dummy + 2 w2 + 1024 w1bf)
    init_kernel<<<1059, 256, 0, stream>>>((int4*)deg, (int4*)(p + (size_t)NN * HID),
                                          mp1_w2, mp2_w2, w2p1, w2p2,
                                          ro_w1, w1bf);

    hist_kernel<<<NE / 256, 256, 0, stream>>>(dst, deg);
    scan_kernel<<<1, 1024, 0, stream>>>(deg, offs, cur);

    // scatter (2176 blocks) ∥ pk layer-1 (2048 blocks)
    scatter_pk_kernel<<<(NE + NN) / 256 + (NN * HID) / 256, 256, 0, stream>>>(
        src, dst, cur, csrp, x, mp1_w1, mp1_b1, p);

    // layer 1
    edge_mfma_kernel<<<NN / 16, 256, 0, stream>>>(p, w2p1, mp1_b2, csrp, offs, cur, x1);
    // layer 2
    pk_kernel<<<(NN * HID) / 256, 256, 0, stream>>>(x1, mp2_w1, mp2_b1, p);
    edge_mfma_kernel<<<NN / 16, 256, 0, stream>>>(p, w2p2, mp2_b2, csrp, offs, cur, x1);

    // readout (p/deg/offs/cur/csrp dead; y1part reuses that region)
    ro1_kernel<<<128, 256, 0, stream>>>(x1, w1bf, y1part);
    relub_kernel<<<64, 256, 0, stream>>>(y1part, ro_b1, y1);
    ro2_kernel<<<512, 256, 0, stream>>>(y1, ro_w2, ro_b2, out);
}